// Round 5
// baseline (365.303 us; speedup 1.0000x reference)
//
#include <hip/hip_runtime.h>

typedef float f4   __attribute__((ext_vector_type(4)));
typedef float f2   __attribute__((ext_vector_type(2)));
typedef _Float16 f16x8 __attribute__((ext_vector_type(8)));
typedef float f32x4  __attribute__((ext_vector_type(4)));

#define N_ROWS  32768
#define D_DIM   256
#define K_CODES 8192
#define NUM_ELEM (N_ROWS * D_DIM)
#define EPS_MARGIN 2e-3f     // fp16 single-pass sieve: key-diff err sigma ~2.6e-4 -> 7.7 sigma
#define FB_CAP  8192
#define FB_RPB  8
#define RF_SLICES 16
#define N_PANELS 256         // 32 codes per panel
#define QTR_PANELS 64        // panels per code-quarter (4 parts)

__device__ __forceinline__ void gl2lds16(const void* g, void* l) {
    __builtin_amdgcn_global_load_lds(
        (const __attribute__((address_space(1))) unsigned int*)g,
        (__attribute__((address_space(3))) unsigned int*)l, 16, 0, 0);
}

// -------- ee[k] = sum_d E[d][k]^2 --------
__global__ void ee_kernel(const float* __restrict__ E, float* __restrict__ ee) {
    const int k = blockIdx.x * blockDim.x + threadIdx.x;
    double s = 0.0;
    for (int d = 0; d < D_DIM; ++d) {
        float v = E[(size_t)d * K_CODES + k];
        s += (double)v * (double)v;
    }
    ee[k] = (float)s;
}

// -------- Ep: panel-major fp16 (LDS-image layout), 16 KB per panel --------
__global__ void prep_kernel(const float* __restrict__ E, short* __restrict__ Ep) {
    const int p  = blockIdx.x;
    const int t  = threadIdx.x;
    const int c  = t & 31;
    const int gq = t >> 5;
    const int cp = p * 32;
    short* ph = Ep + (size_t)p * 8192;
    #pragma unroll
    for (int gi = 0; gi < 4; ++gi) {
        int g = gq * 4 + gi;
        f16x8 h;
        #pragma unroll
        for (int j = 0; j < 8; ++j) {
            float v = E[(size_t)(g * 8 + j) * K_CODES + cp + c];
            h[j] = (_Float16)v;   // RNE cvt
        }
        *(f16x8*)(ph + (g * 32 + c) * 8) = h;
    }
}

// -------- Et32[k][d] = E[d][k] --------
__global__ void trans32_kernel(const float* __restrict__ E, float* __restrict__ Et32) {
    __shared__ float tile[64][65];
    const int t  = threadIdx.x;
    const int k0 = blockIdx.x * 64, d0 = blockIdx.y * 64;
    #pragma unroll
    for (int i = 0; i < 16; ++i) {
        int dd = i * 4 + (t >> 6), kk = t & 63;
        tile[dd][kk] = E[(size_t)(d0 + dd) * K_CODES + k0 + kk];
    }
    __syncthreads();
    #pragma unroll
    for (int i = 0; i < 16; ++i) {
        int kk = i * 4 + (t >> 6), dd = t & 63;
        Et32[(size_t)(k0 + kk) * D_DIM + d0 + dd] = tile[dd][kk];
    }
}

// -------- MFMA sieve (fp16, rt=2, 4 K-quarters for TLP) --------
// grid 1024 = (256 row-tiles x 128 rows) x (4 K-quarters); 4 blocks/CU
__launch_bounds__(256, 4)
__global__ void mfma_sieve_kernel(const float* __restrict__ X,
                                  const short* __restrict__ Ep,
                                  const float* __restrict__ ee,
                                  f2* __restrict__ res_bs,     // [row*4+part] = (best, sec) keys
                                  int* __restrict__ res_idx) { // [row*4+part]
    __shared__ __align__(16) short Bbuf[2][8192];   // 2 x 16 KB
    __shared__ float eebuf[2048];                   // ee slice for this quarter (8 KB)
    const int t    = threadIdx.x;
    const int w    = t >> 6;
    const int lane = t & 63;
    const int n    = lane & 15;
    const int quad = lane >> 4;
    const int part = blockIdx.x & 3;
    const int row0 = (blockIdx.x >> 2) * 128;
    const int rw   = row0 + w * 32;
    const int p0   = part * QTR_PANELS;

    // ---- A fragments (32 rows x 256 d) -> fp16 registers (64 VGPR) ----
    f16x8 Ah[2][8];
    #pragma unroll
    for (int rt = 0; rt < 2; ++rt) {
        const float* xp = X + (size_t)(rw + rt * 16 + n) * D_DIM;
        #pragma unroll
        for (int ks = 0; ks < 8; ++ks) {
            int d = ks * 32 + quad * 8;
            f4 a = *(const f4*)(xp + d);
            f4 b = *(const f4*)(xp + d + 4);
            f16x8 h;
            #pragma unroll
            for (int j = 0; j < 8; ++j) {
                float x = (j < 4) ? a[j] : b[j - 4];
                h[j] = (_Float16)x;
            }
            Ah[rt][ks] = h;
        }
    }

    // ---- stage this quarter's ee into LDS (8 KB) ----
    {
        const f4* src = (const f4*)(ee + part * 2048);
        f4* dst = (f4*)eebuf;
        dst[t * 2]     = src[t * 2];
        dst[t * 2 + 1] = src[t * 2 + 1];
    }

    // max-form top-2 over acc' = dot - ee/2  (min-key == max-acc')
    float bestv[8], secv[8]; int besti[8];
    #pragma unroll
    for (int s = 0; s < 8; ++s) { bestv[s] = -1e30f; secv[s] = -1e30f; besti[s] = 0; }

    {   // prime panel p0 -> buf 0 (16 KB: 4 waves x 4 KB)
        const char* gp = (const char*)Ep + (size_t)p0 * 16384;
        char* lp = (char*)&Bbuf[0][0];
        #pragma unroll
        for (int i = 0; i < 4; ++i)
            gl2lds16(gp + (w * 4 + i) * 1024 + lane * 16, lp + (w * 4 + i) * 1024);
    }
    __syncthreads();

    for (int i = 0; i < QTR_PANELS; ++i) {
        const int p   = p0 + i;
        const int buf = i & 1;
        if (i + 1 < QTR_PANELS) {
            const char* gp = (const char*)Ep + (size_t)(p + 1) * 16384;
            char* lp = (char*)&Bbuf[buf ^ 1][0];
            #pragma unroll
            for (int k = 0; k < 4; ++k)
                gl2lds16(gp + (w * 4 + k) * 1024 + lane * 16, lp + (w * 4 + k) * 1024);
        }

        const short* Bh = &Bbuf[buf][0];
        const int po = i * 32;

        // C-init = -ee/2 (per-ct code column)
        float eh0 = -0.5f * eebuf[po + n];
        float eh1 = -0.5f * eebuf[po + 16 + n];
        f32x4 acc[2][2];
        #pragma unroll
        for (int rt = 0; rt < 2; ++rt) {
            #pragma unroll
            for (int r = 0; r < 4; ++r) { acc[0][rt][r] = eh0; acc[1][rt][r] = eh1; }
        }

        #pragma unroll
        for (int ks = 0; ks < 8; ++ks) {
            const int g = ks * 4 + quad;
            f16x8 bh[2];
            #pragma unroll
            for (int ct = 0; ct < 2; ++ct) {
                int c = ct * 16 + n;
                bh[ct] = *(const f16x8*)(Bh + (g * 32 + c) * 8);
            }
            #pragma unroll
            for (int ct = 0; ct < 2; ++ct)
                #pragma unroll
                for (int rt = 0; rt < 2; ++rt)
                    acc[ct][rt] = __builtin_amdgcn_mfma_f32_16x16x32_f16(Ah[rt][ks], bh[ct], acc[ct][rt], 0, 0, 0);
        }

        const int cb = p * 32;
        #pragma unroll
        for (int ct = 0; ct < 2; ++ct) {
            int code = cb + ct * 16 + n;
            #pragma unroll
            for (int rt = 0; rt < 2; ++rt)
                #pragma unroll
                for (int r = 0; r < 4; ++r) {
                    float av = acc[ct][rt][r];
                    int s = rt * 4 + r;
                    // max-form; strict-> keeps lowest index on ties (codes ascending)
                    float nb = fmaxf(av, bestv[s]);
                    secv[s]  = fmaxf(secv[s], fminf(av, bestv[s]));
                    besti[s] = (av > bestv[s]) ? code : besti[s];
                    bestv[s] = nb;
                }
        }
        __syncthreads();
    }

    // top-2 merge across the 16 'n' lanes (max-form)
    #pragma unroll
    for (int off = 1; off < 16; off <<= 1) {
        #pragma unroll
        for (int s = 0; s < 8; ++s) {
            float ov = __shfl_xor(bestv[s], off);
            int   oi = __shfl_xor(besti[s], off);
            float os = __shfl_xor(secv[s], off);
            bool owin = (ov > bestv[s]) || (ov == bestv[s] && oi < besti[s]);
            if (owin) { secv[s] = fmaxf(os, bestv[s]); bestv[s] = ov; besti[s] = oi; }
            else      { secv[s] = fmaxf(secv[s], ov); }
        }
    }

    if (n == 0) {
        #pragma unroll
        for (int s = 0; s < 8; ++s) {
            int rl  = w * 32 + (s >> 2) * 16 + quad * 4 + (s & 3);
            int row = row0 + rl;
            // convert acc' back to keys: key = -2*acc' (exact, order-reversing)
            f2 bs; bs[0] = -2.0f * bestv[s]; bs[1] = -2.0f * secv[s];
            res_bs[(size_t)row * 4 + part]  = bs;
            res_idx[(size_t)row * 4 + part] = besti[s];
        }
    }
}

// -------- merge quarters: final bidx + EPS flagging --------
__global__ void merge_kernel(const f2* __restrict__ res_bs, const int* __restrict__ res_idx,
                             int* __restrict__ bidx, int* __restrict__ counter,
                             int2* __restrict__ list) {
    const int row = blockIdx.x * blockDim.x + threadIdx.x;
    if (row >= N_ROWS) return;
    float gb = 1e30f, gs = 1e30f; int gi = 0;
    #pragma unroll
    for (int p = 0; p < 4; ++p) {     // ascending code order -> lowest-idx tie keeps first
        f2 v  = res_bs[(size_t)row * 4 + p];
        int vi = res_idx[(size_t)row * 4 + p];
        if (v[0] < gb) { gs = fminf(gb, v[1]); gb = v[0]; gi = vi; }
        else           { gs = fminf(gs, v[0]); }
    }
    bidx[row] = gi;
    if (gs - gb <= EPS_MARGIN) {
        int pos = atomicAdd(counter, 1);
        if (pos < FB_CAP) list[pos] = make_int2(row, gi);
    }
}

// -------- gather + straight-through output + loss (same op order as before) --------
__global__ void gather_kernel(const float* __restrict__ X, const float* __restrict__ Et32,
                              const int* __restrict__ bidx, float* __restrict__ out,
                              double* __restrict__ loss_sum) {
    __shared__ int bl_[128];
    const int t    = threadIdx.x;
    const int row0 = blockIdx.x * 128;
    if (t < 128) bl_[t] = bidx[row0 + t];
    __syncthreads();
    double ls = 0.0;
    const int d = t;
    #pragma unroll 4
    for (int r = 0; r < 128; ++r) {
        int code = bl_[r];
        float q  = Et32[(size_t)code * D_DIM + d];
        float x  = X[(size_t)(row0 + r) * D_DIM + d];
        float dq = q - x;
        out[(size_t)(row0 + r) * D_DIM + d] = x + dq;
        ls += (double)dq * (double)dq;
    }
    #pragma unroll
    for (int off = 32; off > 0; off >>= 1)
        ls += __shfl_down(ls, off);
    if ((t & 63) == 0) atomicAdd(loss_sum, ls);
}

// -------- refine phase 1: fp64 keys over (row-chunk x 16 slices) --------
__global__ void refine1_kernel(const float* __restrict__ X, const float* __restrict__ E,
                               const int* __restrict__ counter, const int2* __restrict__ list,
                               double* __restrict__ res_v, int* __restrict__ res_i) {
    __shared__ float xt[D_DIM][FB_RPB];
    __shared__ int rows_sh[FB_RPB];
    __shared__ double wbv[4][FB_RPB];
    __shared__ int    wbi[4][FB_RPB];

    int nf = *counter; if (nf > FB_CAP) nf = FB_CAP;
    const int nchunks = (nf + FB_RPB - 1) / FB_RPB;
    const int nitems  = nchunks * RF_SLICES;
    const int t = threadIdx.x;

    for (int item = blockIdx.x; item < nitems; item += gridDim.x) {
        const int rc = item / RF_SLICES;
        const int sl = item % RF_SLICES;
        __syncthreads();
        if (t < FB_RPB) {
            int e = rc * FB_RPB + t;
            int2 ent = list[(e < nf) ? e : 0];
            rows_sh[t] = ent.x;
        }
        __syncthreads();
        #pragma unroll
        for (int j = 0; j < FB_RPB; ++j)
            xt[t][j] = X[(size_t)rows_sh[j] * D_DIM + t];
        __syncthreads();

        const int k0 = sl * 512 + t * 2;
        double s0[FB_RPB], s1[FB_RPB], q0 = 0.0, q1 = 0.0;
        #pragma unroll
        for (int j = 0; j < FB_RPB; ++j) { s0[j] = 0.0; s1[j] = 0.0; }
        for (int d = 0; d < D_DIM; ++d) {
            f2 ev = *(const f2*)(E + (size_t)d * K_CODES + k0);
            double e0d = (double)ev[0], e1d = (double)ev[1];
            const f4* xp = (const f4*)(&xt[d][0]);
            f4 xa = xp[0], xb = xp[1];
            double xd[FB_RPB] = { (double)xa[0], (double)xa[1], (double)xa[2], (double)xa[3],
                                  (double)xb[0], (double)xb[1], (double)xb[2], (double)xb[3] };
            q0 += e0d * e0d; q1 += e1d * e1d;
            #pragma unroll
            for (int j = 0; j < FB_RPB; ++j) {
                s0[j] += xd[j] * e0d;
                s1[j] += xd[j] * e1d;
            }
        }
        double bv[FB_RPB]; int bi[FB_RPB];
        #pragma unroll
        for (int j = 0; j < FB_RPB; ++j) {
            double k0v = q0 - 2.0 * s0[j];
            double k1v = q1 - 2.0 * s1[j];
            bv[j] = k0v; bi[j] = k0;
            if (k1v < bv[j]) { bv[j] = k1v; bi[j] = k0 + 1; }
        }
        #pragma unroll
        for (int off = 1; off < 64; off <<= 1) {
            #pragma unroll
            for (int j = 0; j < FB_RPB; ++j) {
                double ov = __shfl_xor(bv[j], off);
                int    oi = __shfl_xor(bi[j], off);
                if (ov < bv[j] || (ov == bv[j] && oi < bi[j])) { bv[j] = ov; bi[j] = oi; }
            }
        }
        const int wave = t >> 6;
        if ((t & 63) == 0) {
            #pragma unroll
            for (int j = 0; j < FB_RPB; ++j) { wbv[wave][j] = bv[j]; wbi[wave][j] = bi[j]; }
        }
        __syncthreads();
        if (t < FB_RPB) {
            double b = wbv[0][t]; int i_ = wbi[0][t];
            #pragma unroll
            for (int wv = 1; wv < 4; ++wv) {
                double ov = wbv[wv][t]; int oi = wbi[wv][t];
                if (ov < b || (ov == b && oi < i_)) { b = ov; i_ = oi; }
            }
            int e = rc * FB_RPB + t;
            res_v[(size_t)e * RF_SLICES + sl] = b;
            res_i[(size_t)e * RF_SLICES + sl] = i_;
        }
    }
}

// -------- refine phase 2: pick fp64 winner, patch row + loss --------
__global__ void patch_kernel(const float* __restrict__ X, const float* __restrict__ Et32,
                             float* __restrict__ out, double* __restrict__ loss_sum,
                             const int* __restrict__ counter, const int2* __restrict__ list,
                             const double* __restrict__ res_v, const int* __restrict__ res_i) {
    int nf = *counter; if (nf > FB_CAP) nf = FB_CAP;
    const int b = blockIdx.x;
    if (b >= nf) return;
    __shared__ int nc_sh;
    const int t = threadIdx.x;
    if (t == 0) {
        double bv = res_v[(size_t)b * RF_SLICES]; int bi = res_i[(size_t)b * RF_SLICES];
        for (int s = 1; s < RF_SLICES; ++s) {
            double v = res_v[(size_t)b * RF_SLICES + s];
            int    i = res_i[(size_t)b * RF_SLICES + s];
            if (v < bv || (v == bv && i < bi)) { bv = v; bi = i; }
        }
        nc_sh = bi;
    }
    __syncthreads();
    int2 ent = list[b];
    const int oc = ent.y, row = ent.x, nc = nc_sh;
    if (nc == oc) return;
    float x  = X[(size_t)row * D_DIM + t];
    float qn = Et32[(size_t)nc * D_DIM + t];
    float qo = Et32[(size_t)oc * D_DIM + t];
    float dqn = qn - x, dqo = qo - x;
    out[(size_t)row * D_DIM + t] = x + dqn;
    double dl = (double)dqn * dqn - (double)dqo * dqo;
    #pragma unroll
    for (int off = 32; off > 0; off >>= 1)
        dl += __shfl_down(dl, off);
    if ((t & 63) == 0) atomicAdd(loss_sum, dl);
}

// -------- finalize loss --------
__global__ void fin_kernel(const double* __restrict__ loss_sum, float* __restrict__ out) {
    double m = loss_sum[0] / (double)NUM_ELEM;
    out[NUM_ELEM] = (float)(0.25 * m + m);
}

extern "C" void kernel_launch(void* const* d_in, const int* in_sizes, int n_in,
                              void* d_out, int out_size, void* d_ws, size_t ws_size,
                              hipStream_t stream) {
    const float* X = (const float*)d_in[0];   // [32,1024,256] fp32
    const float* E = (const float*)d_in[1];   // [256,8192] fp32
    float* out = (float*)d_out;

    // ws layout
    double* loss_sum = (double*)d_ws;                          // 8 B
    int*    counter  = (int*)((char*)d_ws + 8);                // 4 B
    float*  ee       = (float*)((char*)d_ws + 1024);           // 32 KB
    int2*   list     = (int2*)((char*)d_ws + 36864);           // 64 KB
    double* res_v    = (double*)((char*)d_ws + 131072);        // 1 MB
    int*    res_i    = (int*)((char*)d_ws + 1179648);          // 512 KB
    float*  Et32     = (float*)((char*)d_ws + 1703936);        // 8 MB
    short*  Ep       = (short*)((char*)d_ws + 10092544);       // 4 MB (ends 14286848)
    f2*     res_bs   = (f2*)((char*)d_ws + 14286848);          // 1 MB (131072 x f2)
    int*    res_idx  = (int*)((char*)d_ws + 15335424);         // 512 KB
    int*    bidx     = (int*)((char*)d_ws + 19267584);         // 128 KB

    hipMemsetAsync(d_ws, 0, 1024, stream);
    prep_kernel<<<N_PANELS, 256, 0, stream>>>(E, Ep);
    trans32_kernel<<<dim3(128, 4), 256, 0, stream>>>(E, Et32);
    ee_kernel<<<K_CODES / 256, 256, 0, stream>>>(E, ee);
    mfma_sieve_kernel<<<1024, 256, 0, stream>>>(X, Ep, ee, res_bs, res_idx);
    merge_kernel<<<N_ROWS / 256, 256, 0, stream>>>(res_bs, res_idx, bidx, counter, list);
    gather_kernel<<<N_ROWS / 128, 256, 0, stream>>>(X, Et32, bidx, out, loss_sum);
    refine1_kernel<<<2048, 256, 0, stream>>>(X, E, counter, list, res_v, res_i);
    patch_kernel<<<FB_CAP, 256, 0, stream>>>(X, Et32, out, loss_sum, counter, list,
                                             res_v, res_i);
    fin_kernel<<<1, 1, 0, stream>>>(loss_sum, out);
}

// Round 6
// 364.180 us; speedup vs baseline: 1.0031x; 1.0031x over previous
//
#include <hip/hip_runtime.h>

typedef float f4   __attribute__((ext_vector_type(4)));
typedef float f2   __attribute__((ext_vector_type(2)));
typedef _Float16 f16x8 __attribute__((ext_vector_type(8)));
typedef float f32x4  __attribute__((ext_vector_type(4)));

#define N_ROWS  32768
#define D_DIM   256
#define K_CODES 8192
#define NUM_ELEM (N_ROWS * D_DIM)
#define EPS_MARGIN 2e-3f     // fp16 single-pass sieve: key-diff err sigma ~2.6e-4 -> 7.7 sigma
#define FB_CAP  8192
#define FB_RPB  8
#define RF_SLICES 16
#define N_PANELS 256         // 32 codes per panel
#define QTR_PANELS 64        // panels per code-quarter (4 parts)

__device__ __forceinline__ void gl2lds16(const void* g, void* l) {
    __builtin_amdgcn_global_load_lds(
        (const __attribute__((address_space(1))) unsigned int*)g,
        (__attribute__((address_space(3))) unsigned int*)l, 16, 0, 0);
}

// -------- fused prep: Ep (panel-major fp16) + Et32 (E^T fp32) + ee (col sumsq) --------
__global__ void prep_kernel(const float* __restrict__ E, short* __restrict__ Ep,
                            float* __restrict__ Et32, float* __restrict__ ee) {
    __shared__ float eepart[8][32];
    const int p  = blockIdx.x;
    const int t  = threadIdx.x;
    const int c  = t & 31;
    const int gq = t >> 5;
    const int cp = p * 32;
    short* ph = Ep + (size_t)p * 8192;
    float ss = 0.0f;
    #pragma unroll
    for (int gi = 0; gi < 4; ++gi) {
        int g = gq * 4 + gi;
        f16x8 h;
        f4 av, bv;
        #pragma unroll
        for (int j = 0; j < 8; ++j) {
            float v = E[(size_t)(g * 8 + j) * K_CODES + cp + c];
            h[j] = (_Float16)v;   // RNE cvt
            ss += v * v;
            if (j < 4) av[j] = v; else bv[j - 4] = v;
        }
        *(f16x8*)(ph + (g * 32 + c) * 8) = h;
        *(f4*)(Et32 + (size_t)(cp + c) * D_DIM + g * 8)     = av;
        *(f4*)(Et32 + (size_t)(cp + c) * D_DIM + g * 8 + 4) = bv;
    }
    eepart[gq][c] = ss;
    __syncthreads();
    if (t < 32) {
        float s = 0.0f;
        #pragma unroll
        for (int q = 0; q < 8; ++q) s += eepart[q][t];
        ee[cp + t] = s;
    }
}

// -------- MFMA sieve (fp16, rt=2, 4 K-quarters for TLP) --------
// grid 1024 = (256 row-tiles x 128 rows) x (4 K-quarters); 4 blocks/CU via LDS=40KB
// launch_bounds(256,2): proven no-spill regalloc (R1: 68 VGPR); (256,4) spilled (R5)
__launch_bounds__(256, 2)
__global__ void mfma_sieve_kernel(const float* __restrict__ X,
                                  const short* __restrict__ Ep,
                                  const float* __restrict__ ee,
                                  f2* __restrict__ res_bs,     // [row*4+part] = (best, sec) keys
                                  int* __restrict__ res_idx) { // [row*4+part]
    __shared__ __align__(16) short Bbuf[2][8192];   // 2 x 16 KB
    __shared__ float eebuf[2048];                   // ee slice for this quarter (8 KB)
    const int t    = threadIdx.x;
    const int w    = t >> 6;
    const int lane = t & 63;
    const int n    = lane & 15;
    const int quad = lane >> 4;
    const int part = blockIdx.x & 3;
    const int row0 = (blockIdx.x >> 2) * 128;
    const int rw   = row0 + w * 32;
    const int p0   = part * QTR_PANELS;

    // ---- A fragments (32 rows x 256 d) -> fp16 registers (32 VGPR) ----
    f16x8 Ah[2][8];
    #pragma unroll
    for (int rt = 0; rt < 2; ++rt) {
        const float* xp = X + (size_t)(rw + rt * 16 + n) * D_DIM;
        #pragma unroll
        for (int ks = 0; ks < 8; ++ks) {
            int d = ks * 32 + quad * 8;
            f4 a = *(const f4*)(xp + d);
            f4 b = *(const f4*)(xp + d + 4);
            f16x8 h;
            #pragma unroll
            for (int j = 0; j < 8; ++j) {
                float x = (j < 4) ? a[j] : b[j - 4];
                h[j] = (_Float16)x;
            }
            Ah[rt][ks] = h;
        }
    }

    // ---- stage this quarter's ee into LDS (8 KB) ----
    {
        const f4* src = (const f4*)(ee + part * 2048);
        f4* dst = (f4*)eebuf;
        dst[t * 2]     = src[t * 2];
        dst[t * 2 + 1] = src[t * 2 + 1];
    }

    // max-form top-2 over acc' = dot - ee/2  (min-key == max-acc')
    float bestv[8], secv[8]; int besti[8];
    #pragma unroll
    for (int s = 0; s < 8; ++s) { bestv[s] = -1e30f; secv[s] = -1e30f; besti[s] = 0; }

    {   // prime panel p0 -> buf 0 (16 KB: 4 waves x 4 KB)
        const char* gp = (const char*)Ep + (size_t)p0 * 16384;
        char* lp = (char*)&Bbuf[0][0];
        #pragma unroll
        for (int i = 0; i < 4; ++i)
            gl2lds16(gp + (w * 4 + i) * 1024 + lane * 16, lp + (w * 4 + i) * 1024);
    }
    __syncthreads();

    for (int i = 0; i < QTR_PANELS; ++i) {
        const int p   = p0 + i;
        const int buf = i & 1;
        if (i + 1 < QTR_PANELS) {
            const char* gp = (const char*)Ep + (size_t)(p + 1) * 16384;
            char* lp = (char*)&Bbuf[buf ^ 1][0];
            #pragma unroll
            for (int k = 0; k < 4; ++k)
                gl2lds16(gp + (w * 4 + k) * 1024 + lane * 16, lp + (w * 4 + k) * 1024);
        }

        const short* Bh = &Bbuf[buf][0];
        const int po = i * 32;

        // C-init = -ee/2 (per-ct code column)
        float eh0 = -0.5f * eebuf[po + n];
        float eh1 = -0.5f * eebuf[po + 16 + n];
        f32x4 acc[2][2];
        #pragma unroll
        for (int rt = 0; rt < 2; ++rt) {
            #pragma unroll
            for (int r = 0; r < 4; ++r) { acc[0][rt][r] = eh0; acc[1][rt][r] = eh1; }
        }

        #pragma unroll
        for (int ks = 0; ks < 8; ++ks) {
            const int g = ks * 4 + quad;
            f16x8 bh[2];
            #pragma unroll
            for (int ct = 0; ct < 2; ++ct) {
                int c = ct * 16 + n;
                bh[ct] = *(const f16x8*)(Bh + (g * 32 + c) * 8);
            }
            #pragma unroll
            for (int ct = 0; ct < 2; ++ct)
                #pragma unroll
                for (int rt = 0; rt < 2; ++rt)
                    acc[ct][rt] = __builtin_amdgcn_mfma_f32_16x16x32_f16(Ah[rt][ks], bh[ct], acc[ct][rt], 0, 0, 0);
        }

        const int cb = p * 32;
        #pragma unroll
        for (int ct = 0; ct < 2; ++ct) {
            int code = cb + ct * 16 + n;
            #pragma unroll
            for (int rt = 0; rt < 2; ++rt)
                #pragma unroll
                for (int r = 0; r < 4; ++r) {
                    float av = acc[ct][rt][r];
                    int s = rt * 4 + r;
                    // max-form; strict-> keeps lowest index on ties (codes ascending)
                    float nb = fmaxf(av, bestv[s]);
                    secv[s]  = fmaxf(secv[s], fminf(av, bestv[s]));
                    besti[s] = (av > bestv[s]) ? code : besti[s];
                    bestv[s] = nb;
                }
        }
        __syncthreads();
    }

    // top-2 merge across the 16 'n' lanes (max-form)
    #pragma unroll
    for (int off = 1; off < 16; off <<= 1) {
        #pragma unroll
        for (int s = 0; s < 8; ++s) {
            float ov = __shfl_xor(bestv[s], off);
            int   oi = __shfl_xor(besti[s], off);
            float os = __shfl_xor(secv[s], off);
            bool owin = (ov > bestv[s]) || (ov == bestv[s] && oi < besti[s]);
            if (owin) { secv[s] = fmaxf(os, bestv[s]); bestv[s] = ov; besti[s] = oi; }
            else      { secv[s] = fmaxf(secv[s], ov); }
        }
    }

    if (n == 0) {
        #pragma unroll
        for (int s = 0; s < 8; ++s) {
            int rl  = w * 32 + (s >> 2) * 16 + quad * 4 + (s & 3);
            int row = row0 + rl;
            // convert acc' back to keys: key = -2*acc' (exact, order-reversing)
            f2 bs; bs[0] = -2.0f * bestv[s]; bs[1] = -2.0f * secv[s];
            res_bs[(size_t)row * 4 + part]  = bs;
            res_idx[(size_t)row * 4 + part] = besti[s];
        }
    }
}

// -------- fused merge(4 quarters)+flag + gather + straight-through output + loss --------
__global__ void gather_kernel(const float* __restrict__ X, const float* __restrict__ Et32,
                              const f2* __restrict__ res_bs, const int* __restrict__ res_idx,
                              int* __restrict__ counter, int2* __restrict__ list,
                              float* __restrict__ out, double* __restrict__ loss_sum) {
    __shared__ int bl_[128];
    const int t    = threadIdx.x;
    const int row0 = blockIdx.x * 128;
    if (t < 128) {
        const int row = row0 + t;
        float gb = 1e30f, gs = 1e30f; int gi = 0;
        #pragma unroll
        for (int p = 0; p < 4; ++p) {     // ascending code order -> lowest-idx tie keeps first
            f2 v  = res_bs[(size_t)row * 4 + p];
            int vi = res_idx[(size_t)row * 4 + p];
            if (v[0] < gb) { gs = fminf(gb, v[1]); gb = v[0]; gi = vi; }
            else           { gs = fminf(gs, v[0]); }
        }
        bl_[t] = gi;
        if (gs - gb <= EPS_MARGIN) {
            int pos = atomicAdd(counter, 1);
            if (pos < FB_CAP) list[pos] = make_int2(row, gi);
        }
    }
    __syncthreads();
    double ls = 0.0;
    const int d = t;
    #pragma unroll 4
    for (int r = 0; r < 128; ++r) {
        int code = bl_[r];
        float q  = Et32[(size_t)code * D_DIM + d];
        float x  = X[(size_t)(row0 + r) * D_DIM + d];
        float dq = q - x;
        out[(size_t)(row0 + r) * D_DIM + d] = x + dq;
        ls += (double)dq * (double)dq;
    }
    #pragma unroll
    for (int off = 32; off > 0; off >>= 1)
        ls += __shfl_down(ls, off);
    if ((t & 63) == 0) atomicAdd(loss_sum, ls);
}

// -------- refine phase 1: fp64 keys over (row-chunk x 16 slices) --------
__global__ void refine1_kernel(const float* __restrict__ X, const float* __restrict__ E,
                               const int* __restrict__ counter, const int2* __restrict__ list,
                               double* __restrict__ res_v, int* __restrict__ res_i) {
    __shared__ float xt[D_DIM][FB_RPB];
    __shared__ int rows_sh[FB_RPB];
    __shared__ double wbv[4][FB_RPB];
    __shared__ int    wbi[4][FB_RPB];

    int nf = *counter; if (nf > FB_CAP) nf = FB_CAP;
    const int nchunks = (nf + FB_RPB - 1) / FB_RPB;
    const int nitems  = nchunks * RF_SLICES;
    const int t = threadIdx.x;

    for (int item = blockIdx.x; item < nitems; item += gridDim.x) {
        const int rc = item / RF_SLICES;
        const int sl = item % RF_SLICES;
        __syncthreads();
        if (t < FB_RPB) {
            int e = rc * FB_RPB + t;
            int2 ent = list[(e < nf) ? e : 0];
            rows_sh[t] = ent.x;
        }
        __syncthreads();
        #pragma unroll
        for (int j = 0; j < FB_RPB; ++j)
            xt[t][j] = X[(size_t)rows_sh[j] * D_DIM + t];
        __syncthreads();

        const int k0 = sl * 512 + t * 2;
        double s0[FB_RPB], s1[FB_RPB], q0 = 0.0, q1 = 0.0;
        #pragma unroll
        for (int j = 0; j < FB_RPB; ++j) { s0[j] = 0.0; s1[j] = 0.0; }
        for (int d = 0; d < D_DIM; ++d) {
            f2 ev = *(const f2*)(E + (size_t)d * K_CODES + k0);
            double e0d = (double)ev[0], e1d = (double)ev[1];
            const f4* xp = (const f4*)(&xt[d][0]);
            f4 xa = xp[0], xb = xp[1];
            double xd[FB_RPB] = { (double)xa[0], (double)xa[1], (double)xa[2], (double)xa[3],
                                  (double)xb[0], (double)xb[1], (double)xb[2], (double)xb[3] };
            q0 += e0d * e0d; q1 += e1d * e1d;
            #pragma unroll
            for (int j = 0; j < FB_RPB; ++j) {
                s0[j] += xd[j] * e0d;
                s1[j] += xd[j] * e1d;
            }
        }
        double bv[FB_RPB]; int bi[FB_RPB];
        #pragma unroll
        for (int j = 0; j < FB_RPB; ++j) {
            double k0v = q0 - 2.0 * s0[j];
            double k1v = q1 - 2.0 * s1[j];
            bv[j] = k0v; bi[j] = k0;
            if (k1v < bv[j]) { bv[j] = k1v; bi[j] = k0 + 1; }
        }
        #pragma unroll
        for (int off = 1; off < 64; off <<= 1) {
            #pragma unroll
            for (int j = 0; j < FB_RPB; ++j) {
                double ov = __shfl_xor(bv[j], off);
                int    oi = __shfl_xor(bi[j], off);
                if (ov < bv[j] || (ov == bv[j] && oi < bi[j])) { bv[j] = ov; bi[j] = oi; }
            }
        }
        const int wave = t >> 6;
        if ((t & 63) == 0) {
            #pragma unroll
            for (int j = 0; j < FB_RPB; ++j) { wbv[wave][j] = bv[j]; wbi[wave][j] = bi[j]; }
        }
        __syncthreads();
        if (t < FB_RPB) {
            double b = wbv[0][t]; int i_ = wbi[0][t];
            #pragma unroll
            for (int wv = 1; wv < 4; ++wv) {
                double ov = wbv[wv][t]; int oi = wbi[wv][t];
                if (ov < b || (ov == b && oi < i_)) { b = ov; i_ = oi; }
            }
            int e = rc * FB_RPB + t;
            res_v[(size_t)e * RF_SLICES + sl] = b;
            res_i[(size_t)e * RF_SLICES + sl] = i_;
        }
    }
}

// -------- refine phase 2: pick fp64 winner, patch row + loss --------
__global__ void patch_kernel(const float* __restrict__ X, const float* __restrict__ Et32,
                             float* __restrict__ out, double* __restrict__ loss_sum,
                             const int* __restrict__ counter, const int2* __restrict__ list,
                             const double* __restrict__ res_v, const int* __restrict__ res_i) {
    int nf = *counter; if (nf > FB_CAP) nf = FB_CAP;
    const int b = blockIdx.x;
    if (b >= nf) return;
    __shared__ int nc_sh;
    const int t = threadIdx.x;
    if (t == 0) {
        double bv = res_v[(size_t)b * RF_SLICES]; int bi = res_i[(size_t)b * RF_SLICES];
        for (int s = 1; s < RF_SLICES; ++s) {
            double v = res_v[(size_t)b * RF_SLICES + s];
            int    i = res_i[(size_t)b * RF_SLICES + s];
            if (v < bv || (v == bv && i < bi)) { bv = v; bi = i; }
        }
        nc_sh = bi;
    }
    __syncthreads();
    int2 ent = list[b];
    const int oc = ent.y, row = ent.x, nc = nc_sh;
    if (nc == oc) return;
    float x  = X[(size_t)row * D_DIM + t];
    float qn = Et32[(size_t)nc * D_DIM + t];
    float qo = Et32[(size_t)oc * D_DIM + t];
    float dqn = qn - x, dqo = qo - x;
    out[(size_t)row * D_DIM + t] = x + dqn;
    double dl = (double)dqn * dqn - (double)dqo * dqo;
    #pragma unroll
    for (int off = 32; off > 0; off >>= 1)
        dl += __shfl_down(dl, off);
    if ((t & 63) == 0) atomicAdd(loss_sum, dl);
}

// -------- finalize loss --------
__global__ void fin_kernel(const double* __restrict__ loss_sum, float* __restrict__ out) {
    double m = loss_sum[0] / (double)NUM_ELEM;
    out[NUM_ELEM] = (float)(0.25 * m + m);
}

extern "C" void kernel_launch(void* const* d_in, const int* in_sizes, int n_in,
                              void* d_out, int out_size, void* d_ws, size_t ws_size,
                              hipStream_t stream) {
    const float* X = (const float*)d_in[0];   // [32,1024,256] fp32
    const float* E = (const float*)d_in[1];   // [256,8192] fp32
    float* out = (float*)d_out;

    // ws layout
    double* loss_sum = (double*)d_ws;                          // 8 B
    int*    counter  = (int*)((char*)d_ws + 8);                // 4 B
    float*  ee       = (float*)((char*)d_ws + 1024);           // 32 KB
    int2*   list     = (int2*)((char*)d_ws + 36864);           // 64 KB
    double* res_v    = (double*)((char*)d_ws + 131072);        // 1 MB
    int*    res_i    = (int*)((char*)d_ws + 1179648);          // 512 KB
    float*  Et32     = (float*)((char*)d_ws + 1703936);        // 8 MB
    short*  Ep       = (short*)((char*)d_ws + 10092544);       // 4 MB (ends 14286848)
    f2*     res_bs   = (f2*)((char*)d_ws + 14286848);          // 1 MB (131072 x f2)
    int*    res_idx  = (int*)((char*)d_ws + 15335424);         // 512 KB

    hipMemsetAsync(d_ws, 0, 1024, stream);
    prep_kernel<<<N_PANELS, 256, 0, stream>>>(E, Ep, Et32, ee);
    mfma_sieve_kernel<<<1024, 256, 0, stream>>>(X, Ep, ee, res_bs, res_idx);
    gather_kernel<<<N_ROWS / 128, 256, 0, stream>>>(X, Et32, res_bs, res_idx,
                                                    counter, list, out, loss_sum);
    refine1_kernel<<<2048, 256, 0, stream>>>(X, E, counter, list, res_v, res_i);
    patch_kernel<<<FB_CAP, 256, 0, stream>>>(X, Et32, out, loss_sum, counter, list,
                                             res_v, res_i);
    fin_kernel<<<1, 1, 0, stream>>>(loss_sum, out);
}

// Round 7
// 326.140 us; speedup vs baseline: 1.1201x; 1.1166x over previous
//
#include <hip/hip_runtime.h>

typedef float f4   __attribute__((ext_vector_type(4)));
typedef float f2   __attribute__((ext_vector_type(2)));
typedef _Float16 f16x8 __attribute__((ext_vector_type(8)));
typedef float f32x4  __attribute__((ext_vector_type(4)));

#define N_ROWS  32768
#define D_DIM   256
#define K_CODES 8192
#define NUM_ELEM (N_ROWS * D_DIM)
#define EPS_MARGIN 2e-3f     // fp16 single-pass sieve: key-diff err sigma ~2.6e-4 -> 7.7 sigma
#define FB_CAP  8192
#define FB_RPB  8
#define RF_SLICES 16
#define N_PANELS 256         // 32 codes per panel
#define HALF_PANELS 128      // panels per code-half

__device__ __forceinline__ void gl2lds16(const void* g, void* l) {
    __builtin_amdgcn_global_load_lds(
        (const __attribute__((address_space(1))) unsigned int*)g,
        (__attribute__((address_space(3))) unsigned int*)l, 16, 0, 0);
}

// -------- fused prep: Ep (panel-major fp16) + Et32 (E^T fp32) + ee (col sumsq) --------
__global__ void prep_kernel(const float* __restrict__ E, short* __restrict__ Ep,
                            float* __restrict__ Et32, float* __restrict__ ee) {
    __shared__ float eepart[8][32];
    const int p  = blockIdx.x;
    const int t  = threadIdx.x;
    const int c  = t & 31;
    const int gq = t >> 5;
    const int cp = p * 32;
    short* ph = Ep + (size_t)p * 8192;
    float ss = 0.0f;
    #pragma unroll
    for (int gi = 0; gi < 4; ++gi) {
        int g = gq * 4 + gi;
        f16x8 h;
        f4 av, bv;
        #pragma unroll
        for (int j = 0; j < 8; ++j) {
            float v = E[(size_t)(g * 8 + j) * K_CODES + cp + c];
            h[j] = (_Float16)v;   // RNE cvt
            ss += v * v;
            if (j < 4) av[j] = v; else bv[j - 4] = v;
        }
        *(f16x8*)(ph + (g * 32 + c) * 8) = h;
        *(f4*)(Et32 + (size_t)(cp + c) * D_DIM + g * 8)     = av;
        *(f4*)(Et32 + (size_t)(cp + c) * D_DIM + g * 8 + 4) = bv;
    }
    eepart[gq][c] = ss;
    __syncthreads();
    if (t < 32) {
        float s = 0.0f;
        #pragma unroll
        for (int q = 0; q < 8; ++q) s += eepart[q][t];
        ee[cp + t] = s;
    }
}

// -------- MFMA sieve (R1-proven config): grid 512 = (256 row-tiles x 128 rows) x (2 halves) --------
__launch_bounds__(256, 2)
__global__ void mfma_sieve_kernel(const float* __restrict__ X,
                                  const short* __restrict__ Ep,
                                  const float* __restrict__ ee,
                                  f2* __restrict__ res_bs,     // [row*2+half] = (best, sec)
                                  int* __restrict__ res_idx) { // [row*2+half]
    __shared__ __align__(16) short Bbuf[2][8192];   // 2 x 16 KB
    const int t    = threadIdx.x;
    const int w    = t >> 6;
    const int lane = t & 63;
    const int n    = lane & 15;
    const int quad = lane >> 4;
    const int half = blockIdx.x & 1;
    const int row0 = (blockIdx.x >> 1) * 128;
    const int rw   = row0 + w * 32;
    const int p0   = half * HALF_PANELS;

    // ---- A fragments (32 rows x 256 d) -> fp16 registers ----
    f16x8 Ah[2][8];
    #pragma unroll
    for (int rt = 0; rt < 2; ++rt) {
        const float* xp = X + (size_t)(rw + rt * 16 + n) * D_DIM;
        #pragma unroll
        for (int ks = 0; ks < 8; ++ks) {
            int d = ks * 32 + quad * 8;
            f4 a = *(const f4*)(xp + d);
            f4 b = *(const f4*)(xp + d + 4);
            f16x8 h;
            #pragma unroll
            for (int j = 0; j < 8; ++j) {
                float x = (j < 4) ? a[j] : b[j - 4];
                h[j] = (_Float16)x;
            }
            Ah[rt][ks] = h;
        }
    }

    float bestv[8], secv[8]; int besti[8];
    #pragma unroll
    for (int s = 0; s < 8; ++s) { bestv[s] = 1e30f; secv[s] = 1e30f; besti[s] = 0; }

    {   // prime panel p0 -> buf 0 (16 KB: 4 waves x 4 KB)
        const char* gp = (const char*)Ep + (size_t)p0 * 16384;
        char* lp = (char*)&Bbuf[0][0];
        #pragma unroll
        for (int i = 0; i < 4; ++i)
            gl2lds16(gp + (w * 4 + i) * 1024 + lane * 16, lp + (w * 4 + i) * 1024);
    }
    __syncthreads();

    for (int i = 0; i < HALF_PANELS; ++i) {
        const int p   = p0 + i;
        const int buf = i & 1;
        if (i + 1 < HALF_PANELS) {
            const char* gp = (const char*)Ep + (size_t)(p + 1) * 16384;
            char* lp = (char*)&Bbuf[buf ^ 1][0];
            #pragma unroll
            for (int k = 0; k < 4; ++k)
                gl2lds16(gp + (w * 4 + k) * 1024 + lane * 16, lp + (w * 4 + k) * 1024);
        }

        const short* Bh = &Bbuf[buf][0];

        f32x4 acc[2][2];
        #pragma unroll
        for (int ct = 0; ct < 2; ++ct)
            #pragma unroll
            for (int rt = 0; rt < 2; ++rt)
                acc[ct][rt] = (f32x4)(0.0f);

        #pragma unroll
        for (int ks = 0; ks < 8; ++ks) {
            const int g = ks * 4 + quad;
            f16x8 bh[2];
            #pragma unroll
            for (int ct = 0; ct < 2; ++ct) {
                int c = ct * 16 + n;
                bh[ct] = *(const f16x8*)(Bh + (g * 32 + c) * 8);
            }
            #pragma unroll
            for (int ct = 0; ct < 2; ++ct)
                #pragma unroll
                for (int rt = 0; rt < 2; ++rt)
                    acc[ct][rt] = __builtin_amdgcn_mfma_f32_16x16x32_f16(Ah[rt][ks], bh[ct], acc[ct][rt], 0, 0, 0);
        }

        const int cb = p * 32;
        #pragma unroll
        for (int ct = 0; ct < 2; ++ct) {
            int code = cb + ct * 16 + n;
            float eev = ee[code];
            #pragma unroll
            for (int rt = 0; rt < 2; ++rt)
                #pragma unroll
                for (int r = 0; r < 4; ++r) {
                    float key = fmaf(-2.0f, acc[ct][rt][r], eev);
                    int s = rt * 4 + r;
                    // min/max form; strict-< index semantics preserved
                    float nb = fminf(key, bestv[s]);
                    secv[s]  = fminf(secv[s], fmaxf(key, bestv[s]));
                    besti[s] = (key < bestv[s]) ? code : besti[s];
                    bestv[s] = nb;
                }
        }
        __syncthreads();
    }

    // top-2 merge across the 16 'n' lanes
    #pragma unroll
    for (int off = 1; off < 16; off <<= 1) {
        #pragma unroll
        for (int s = 0; s < 8; ++s) {
            float ov = __shfl_xor(bestv[s], off);
            int   oi = __shfl_xor(besti[s], off);
            float os = __shfl_xor(secv[s], off);
            bool owin = (ov < bestv[s]) || (ov == bestv[s] && oi < besti[s]);
            if (owin) { secv[s] = fminf(os, bestv[s]); bestv[s] = ov; besti[s] = oi; }
            else      { secv[s] = fminf(secv[s], ov); }
        }
    }

    if (n == 0) {
        #pragma unroll
        for (int s = 0; s < 8; ++s) {
            int rl  = w * 32 + (s >> 2) * 16 + quad * 4 + (s & 3);
            int row = row0 + rl;
            f2 bs; bs[0] = bestv[s]; bs[1] = secv[s];
            res_bs[(size_t)row * 2 + half]  = bs;
            res_idx[(size_t)row * 2 + half] = besti[s];
        }
    }
}

// -------- fused merge(2 halves)+flag + gather + straight-through output + loss --------
__global__ void gather_kernel(const float* __restrict__ X, const float* __restrict__ Et32,
                              const f2* __restrict__ res_bs, const int* __restrict__ res_idx,
                              int* __restrict__ counter, int2* __restrict__ list,
                              float* __restrict__ out, double* __restrict__ loss_sum) {
    __shared__ int bl_[128];
    const int t    = threadIdx.x;
    const int row0 = blockIdx.x * 128;
    if (t < 128) {
        const int row = row0 + t;
        f2 a = res_bs[(size_t)row * 2];      // half 0 (indices < half 1's)
        f2 b = res_bs[(size_t)row * 2 + 1];
        int ia = res_idx[(size_t)row * 2];
        int ib = res_idx[(size_t)row * 2 + 1];
        float gb; int gi; float gs;
        if (b[0] < a[0]) { gb = b[0]; gi = ib; gs = fminf(b[1], a[0]); }
        else             { gb = a[0]; gi = ia; gs = fminf(a[1], b[0]); }  // tie -> half 0 (lower idx)
        bl_[t] = gi;
        if (gs - gb <= EPS_MARGIN) {
            int pos = atomicAdd(counter, 1);
            if (pos < FB_CAP) list[pos] = make_int2(row, gi);
        }
    }
    __syncthreads();
    double ls = 0.0;
    const int d = t;
    #pragma unroll 4
    for (int r = 0; r < 128; ++r) {
        int code = bl_[r];
        float q  = Et32[(size_t)code * D_DIM + d];
        float x  = X[(size_t)(row0 + r) * D_DIM + d];
        float dq = q - x;
        out[(size_t)(row0 + r) * D_DIM + d] = x + dq;
        ls += (double)dq * (double)dq;
    }
    #pragma unroll
    for (int off = 32; off > 0; off >>= 1)
        ls += __shfl_down(ls, off);
    if ((t & 63) == 0) atomicAdd(loss_sum, ls);
}

// -------- refine phase 1: fp64 keys over (row-chunk x 16 slices) --------
__global__ void refine1_kernel(const float* __restrict__ X, const float* __restrict__ E,
                               const int* __restrict__ counter, const int2* __restrict__ list,
                               double* __restrict__ res_v, int* __restrict__ res_i) {
    __shared__ float xt[D_DIM][FB_RPB];
    __shared__ int rows_sh[FB_RPB];
    __shared__ double wbv[4][FB_RPB];
    __shared__ int    wbi[4][FB_RPB];

    int nf = *counter; if (nf > FB_CAP) nf = FB_CAP;
    const int nchunks = (nf + FB_RPB - 1) / FB_RPB;
    const int nitems  = nchunks * RF_SLICES;
    const int t = threadIdx.x;

    for (int item = blockIdx.x; item < nitems; item += gridDim.x) {
        const int rc = item / RF_SLICES;
        const int sl = item % RF_SLICES;
        __syncthreads();
        if (t < FB_RPB) {
            int e = rc * FB_RPB + t;
            int2 ent = list[(e < nf) ? e : 0];
            rows_sh[t] = ent.x;
        }
        __syncthreads();
        #pragma unroll
        for (int j = 0; j < FB_RPB; ++j)
            xt[t][j] = X[(size_t)rows_sh[j] * D_DIM + t];
        __syncthreads();

        const int k0 = sl * 512 + t * 2;
        double s0[FB_RPB], s1[FB_RPB], q0 = 0.0, q1 = 0.0;
        #pragma unroll
        for (int j = 0; j < FB_RPB; ++j) { s0[j] = 0.0; s1[j] = 0.0; }
        for (int d = 0; d < D_DIM; ++d) {
            f2 ev = *(const f2*)(E + (size_t)d * K_CODES + k0);
            double e0d = (double)ev[0], e1d = (double)ev[1];
            const f4* xp = (const f4*)(&xt[d][0]);
            f4 xa = xp[0], xb = xp[1];
            double xd[FB_RPB] = { (double)xa[0], (double)xa[1], (double)xa[2], (double)xa[3],
                                  (double)xb[0], (double)xb[1], (double)xb[2], (double)xb[3] };
            q0 += e0d * e0d; q1 += e1d * e1d;
            #pragma unroll
            for (int j = 0; j < FB_RPB; ++j) {
                s0[j] += xd[j] * e0d;
                s1[j] += xd[j] * e1d;
            }
        }
        double bv[FB_RPB]; int bi[FB_RPB];
        #pragma unroll
        for (int j = 0; j < FB_RPB; ++j) {
            double k0v = q0 - 2.0 * s0[j];
            double k1v = q1 - 2.0 * s1[j];
            bv[j] = k0v; bi[j] = k0;
            if (k1v < bv[j]) { bv[j] = k1v; bi[j] = k0 + 1; }
        }
        #pragma unroll
        for (int off = 1; off < 64; off <<= 1) {
            #pragma unroll
            for (int j = 0; j < FB_RPB; ++j) {
                double ov = __shfl_xor(bv[j], off);
                int    oi = __shfl_xor(bi[j], off);
                if (ov < bv[j] || (ov == bv[j] && oi < bi[j])) { bv[j] = ov; bi[j] = oi; }
            }
        }
        const int wave = t >> 6;
        if ((t & 63) == 0) {
            #pragma unroll
            for (int j = 0; j < FB_RPB; ++j) { wbv[wave][j] = bv[j]; wbi[wave][j] = bi[j]; }
        }
        __syncthreads();
        if (t < FB_RPB) {
            double b = wbv[0][t]; int i_ = wbi[0][t];
            #pragma unroll
            for (int wv = 1; wv < 4; ++wv) {
                double ov = wbv[wv][t]; int oi = wbi[wv][t];
                if (ov < b || (ov == b && oi < i_)) { b = ov; i_ = oi; }
            }
            int e = rc * FB_RPB + t;
            res_v[(size_t)e * RF_SLICES + sl] = b;
            res_i[(size_t)e * RF_SLICES + sl] = i_;
        }
    }
}

// -------- refine phase 2: pick fp64 winner, patch row + loss --------
__global__ void patch_kernel(const float* __restrict__ X, const float* __restrict__ Et32,
                             float* __restrict__ out, double* __restrict__ loss_sum,
                             const int* __restrict__ counter, const int2* __restrict__ list,
                             const double* __restrict__ res_v, const int* __restrict__ res_i) {
    int nf = *counter; if (nf > FB_CAP) nf = FB_CAP;
    const int b = blockIdx.x;
    if (b >= nf) return;
    __shared__ int nc_sh;
    const int t = threadIdx.x;
    if (t == 0) {
        double bv = res_v[(size_t)b * RF_SLICES]; int bi = res_i[(size_t)b * RF_SLICES];
        for (int s = 1; s < RF_SLICES; ++s) {
            double v = res_v[(size_t)b * RF_SLICES + s];
            int    i = res_i[(size_t)b * RF_SLICES + s];
            if (v < bv || (v == bv && i < bi)) { bv = v; bi = i; }
        }
        nc_sh = bi;
    }
    __syncthreads();
    int2 ent = list[b];
    const int oc = ent.y, row = ent.x, nc = nc_sh;
    if (nc == oc) return;
    float x  = X[(size_t)row * D_DIM + t];
    float qn = Et32[(size_t)nc * D_DIM + t];
    float qo = Et32[(size_t)oc * D_DIM + t];
    float dqn = qn - x, dqo = qo - x;
    out[(size_t)row * D_DIM + t] = x + dqn;
    double dl = (double)dqn * dqn - (double)dqo * dqo;
    #pragma unroll
    for (int off = 32; off > 0; off >>= 1)
        dl += __shfl_down(dl, off);
    if ((t & 63) == 0) atomicAdd(loss_sum, dl);
}

// -------- finalize loss --------
__global__ void fin_kernel(const double* __restrict__ loss_sum, float* __restrict__ out) {
    double m = loss_sum[0] / (double)NUM_ELEM;
    out[NUM_ELEM] = (float)(0.25 * m + m);
}

extern "C" void kernel_launch(void* const* d_in, const int* in_sizes, int n_in,
                              void* d_out, int out_size, void* d_ws, size_t ws_size,
                              hipStream_t stream) {
    const float* X = (const float*)d_in[0];   // [32,1024,256] fp32
    const float* E = (const float*)d_in[1];   // [256,8192] fp32
    float* out = (float*)d_out;

    // ws layout
    double* loss_sum = (double*)d_ws;                          // 8 B
    int*    counter  = (int*)((char*)d_ws + 8);                // 4 B
    float*  ee       = (float*)((char*)d_ws + 1024);           // 32 KB
    int2*   list     = (int2*)((char*)d_ws + 36864);           // 64 KB
    double* res_v    = (double*)((char*)d_ws + 131072);        // 1 MB
    int*    res_i    = (int*)((char*)d_ws + 1179648);          // 512 KB
    float*  Et32     = (float*)((char*)d_ws + 1703936);        // 8 MB
    short*  Ep       = (short*)((char*)d_ws + 10092544);       // 4 MB (ends 14286848)
    f2*     res_bs   = (f2*)((char*)d_ws + 14286848);          // 512 KB (65536 x f2)
    int*    res_idx  = (int*)((char*)d_ws + 15335424);         // 256 KB

    hipMemsetAsync(d_ws, 0, 1024, stream);
    prep_kernel<<<N_PANELS, 256, 0, stream>>>(E, Ep, Et32, ee);
    mfma_sieve_kernel<<<512, 256, 0, stream>>>(X, Ep, ee, res_bs, res_idx);
    gather_kernel<<<N_ROWS / 128, 256, 0, stream>>>(X, Et32, res_bs, res_idx,
                                                    counter, list, out, loss_sum);
    refine1_kernel<<<2048, 256, 0, stream>>>(X, E, counter, list, res_v, res_i);
    patch_kernel<<<FB_CAP, 256, 0, stream>>>(X, Et32, out, loss_sum, counter, list,
                                             res_v, res_i);
    fin_kernel<<<1, 1, 0, stream>>>(loss_sum, out);
}